// Round 11
// baseline (198.767 us; speedup 1.0000x reference)
//
#include <hip/hip_runtime.h>

// 2-layer GCN. LDS-multisplit CSR build + bf16 MFMA gemm1 + eighth-wave fused1.
// Pipeline:
//  A k_hist     : per-block LDS hist over NB dst-buckets (bucket = dst>>8)
//  B k_bscan    : per-bucket exclusive scan over the 256 blocks
//  C k_cscan    : exclusive scan of bucket totals -> bucket bases; + packs W1
//                 into bf16 B-fragments (merged to save a launch)
//  D k_dscatter : scatter packed (src<<8|dst&255) into bucket-grouped array
//  E k_bfill    : per-bucket node hist+scan -> offs/dinv; csr via LDS staging
//  F k_gemm1m   : pp = (x@W1)*dinv[row] via v_mfma_f32_16x16x32_bf16, bf16 store
//  G k_fused1   : wave/node, 8 lanes x 16B per edge, 4 gathers in flight;
//                 h=relu(dinv*acc+b1); qp=(h.W2)*dinv
//  H k_fused2   : thread/node, 4 qp-gathers in flight;
//                 out = dinv*(qp[self]+sum qp[csr]) + b2
//
// gfx950 NOTES: __shfl = ds_bpermute (source lane must be exec-active; all
// shuffles run full-exec with wave-uniform lane args). No per-edge LDS atomics
// (R6: 10x slower than register accumulation). MFMA 16x16x32 bf16 layouts:
// A row=l&15,k=(l>>4)*8+j; B col=l&15,k=(l>>4)*8+j; C/D col=lane&15,
// row=(lane>>4)*4+reg (m89-verified, confirmed by R8 absmax).
// fused1 is gather-latency-bound (R10: 67MB FETCH, nothing saturated) ->
// maximize loads-in-flight with widest (dwordx4) gathers.

#define NBLK 256
#define MAXB 8192

typedef __attribute__((ext_vector_type(8))) short bf16x8;
typedef __attribute__((ext_vector_type(4))) float f32x4;

__device__ __forceinline__ float bf2f(unsigned short u) {
    union { unsigned int i; float f; } v; v.i = ((unsigned int)u) << 16; return v.f;
}
__device__ __forceinline__ unsigned short f2bf(float f) {
    union { float f; unsigned int i; } v; v.f = f;
    unsigned int r = (v.i + 0x7fffu + ((v.i >> 16) & 1u)) >> 16;
    return (unsigned short)r;
}

// A: per-block histogram of dst buckets
__global__ __launch_bounds__(256) void k_hist(const int* __restrict__ dst, int E, int chunk,
                                              int NB, int* __restrict__ bh) {
    __shared__ int h[512];
    int blk = blockIdx.x, t = threadIdx.x;
    h[t] = 0; h[t + 256] = 0;
    __syncthreads();
    int e0 = blk * chunk, e1 = min(E, e0 + chunk);
    for (int e = e0 + t; e < e1; e += 256) atomicAdd(&h[dst[e] >> 8], 1);
    __syncthreads();
    for (int k = t; k < NB; k += 256) bh[blk * NB + k] = h[k];
}

// B: per-bucket exclusive scan over NBLK block counts
__global__ __launch_bounds__(256) void k_bscan(int* __restrict__ bh, int NB,
                                               int* __restrict__ btot) {
    __shared__ int s[256];
    int k = blockIdx.x, t = threadIdx.x;
    int v = bh[t * NB + k];
    s[t] = v;
    __syncthreads();
    for (int off = 1; off < 256; off <<= 1) {
        int u = (t >= off) ? s[t - off] : 0;
        __syncthreads();
        s[t] += u;
        __syncthreads();
    }
    bh[t * NB + k] = s[t] - v;
    if (t == 255) btot[k] = s[255];
}

// C: exclusive scan of bucket totals (NB <= 512) + W1 -> Bfrag pack (merged)
__global__ __launch_bounds__(512) void k_cscan(const int* __restrict__ btot, int NB, int E,
                                               int* __restrict__ bbase, int* __restrict__ offs,
                                               int N, const float* __restrict__ W1,
                                               unsigned short* __restrict__ Bfrag) {
    __shared__ int s[512];
    int t = threadIdx.x;
    int v = (t < NB) ? btot[t] : 0;
    s[t] = v;
    __syncthreads();
    for (int off = 1; off < 512; off <<= 1) {
        int u = (t >= off) ? s[t - off] : 0;
        __syncthreads();
        s[t] += u;
        __syncthreads();
    }
    if (t < NB) bbase[t] = s[t] - v;
    if (t == 0) offs[N] = E;
    // independent: pack W1 into B-fragment order
    for (int i = t; i < 8192; i += 512) {
        int j    = i & 7;
        int lane = (i >> 3) & 63;
        int ks   = (i >> 9) & 3;
        int nt   = i >> 11;
        int k = ks * 32 + ((lane >> 4) << 3) + j;
        int n = nt * 16 + (lane & 15);
        Bfrag[i] = f2bf(W1[k * 64 + n]);
    }
}

// D: scatter packed records into bucket-grouped order (LDS cursors)
__global__ __launch_bounds__(256) void k_dscatter(const int* __restrict__ src,
                                                  const int* __restrict__ dst, int E, int chunk,
                                                  const int* __restrict__ bh,
                                                  const int* __restrict__ bbase, int NB,
                                                  unsigned int* __restrict__ grouped) {
    __shared__ int cur[512];
    int blk = blockIdx.x, t = threadIdx.x;
    for (int k = t; k < NB; k += 256) cur[k] = bbase[k] + bh[blk * NB + k];
    __syncthreads();
    int e0 = blk * chunk, e1 = min(E, e0 + chunk);
    for (int e = e0 + t; e < e1; e += 256) {
        int d = dst[e];
        int pos = atomicAdd(&cur[d >> 8], 1);
        grouped[pos] = ((unsigned int)src[e] << 8) | (unsigned int)(d & 255);
    }
}

// E: per-bucket node hist/scan -> offs, dinv; csr fill via LDS staging
__global__ __launch_bounds__(256) void k_bfill(const unsigned int* __restrict__ grouped,
                                               const int* __restrict__ bbase,
                                               const int* __restrict__ btot, int N,
                                               int* __restrict__ offs, int* __restrict__ csr,
                                               float* __restrict__ dinv) {
    __shared__ int hist[256], pfx[256], cur[256];
    __shared__ int stage[MAXB];
    int k = blockIdx.x, t = threadIdx.x;
    int base = bbase[k], cnt = btot[k];
    hist[t] = 0;
    __syncthreads();
    for (int i = t; i < cnt; i += 256) atomicAdd(&hist[grouped[base + i] & 255u], 1);
    __syncthreads();
    int v = hist[t];
    pfx[t] = v;
    __syncthreads();
    for (int off = 1; off < 256; off <<= 1) {
        int u = (t >= off) ? pfx[t - off] : 0;
        __syncthreads();
        pfx[t] += u;
        __syncthreads();
    }
    int excl = pfx[t] - v;
    cur[t] = excl;
    int node = (k << 8) + t;
    if (node < N) {
        offs[node] = base + excl;
        dinv[node] = rsqrtf((float)v + 1.0f);
    }
    __syncthreads();
    if (cnt <= MAXB) {
        for (int i = t; i < cnt; i += 256) {
            unsigned int p = grouped[base + i];
            int pos = atomicAdd(&cur[p & 255u], 1);
            stage[pos] = (int)(p >> 8);
        }
        __syncthreads();
        for (int i = t; i < cnt; i += 256) csr[base + i] = stage[i];
    } else {
        for (int i = t; i < cnt; i += 256) {
            unsigned int p = grouped[base + i];
            int pos = atomicAdd(&cur[p & 255u], 1);
            csr[base + pos] = (int)(p >> 8);
        }
    }
}

// F: MFMA gemm1. Block = 4 waves x 16 rows = 64 rows, all 64 cols. No LDS.
__global__ __launch_bounds__(256) void k_gemm1m(
    const float* __restrict__ x, const unsigned short* __restrict__ Bfrag,
    const float* __restrict__ dinv, unsigned short* __restrict__ ppb, int N)
{
    int lane = threadIdx.x & 63;
    int wid = threadIdx.x >> 6;
    int r0 = blockIdx.x * 64 + wid * 16;
    int arow = r0 + (lane & 15);
    if (arow > N - 1) arow = N - 1;              // clamp (stores guarded)
    const float* xrow = x + (size_t)arow * 128 + ((lane >> 4) << 3);

    f32x4 acc0 = {0.f, 0.f, 0.f, 0.f};
    f32x4 acc1 = {0.f, 0.f, 0.f, 0.f};
    f32x4 acc2 = {0.f, 0.f, 0.f, 0.f};
    f32x4 acc3 = {0.f, 0.f, 0.f, 0.f};

    #pragma unroll
    for (int ks = 0; ks < 4; ks++) {
        float4 a0 = *(const float4*)(xrow + ks * 32);
        float4 a1 = *(const float4*)(xrow + ks * 32 + 4);
        bf16x8 a;
        a[0] = (short)f2bf(a0.x); a[1] = (short)f2bf(a0.y);
        a[2] = (short)f2bf(a0.z); a[3] = (short)f2bf(a0.w);
        a[4] = (short)f2bf(a1.x); a[5] = (short)f2bf(a1.y);
        a[6] = (short)f2bf(a1.z); a[7] = (short)f2bf(a1.w);
        const bf16x8* bp = (const bf16x8*)(Bfrag + (size_t)ks * 64 * 8 + lane * 8);
        acc0 = __builtin_amdgcn_mfma_f32_16x16x32_bf16(a, bp[0 * 256], acc0, 0, 0, 0);
        acc1 = __builtin_amdgcn_mfma_f32_16x16x32_bf16(a, bp[1 * 256], acc1, 0, 0, 0);
        acc2 = __builtin_amdgcn_mfma_f32_16x16x32_bf16(a, bp[2 * 256], acc2, 0, 0, 0);
        acc3 = __builtin_amdgcn_mfma_f32_16x16x32_bf16(a, bp[3 * 256], acc3, 0, 0, 0);
    }

    int c = lane & 15;
    int rbase = r0 + ((lane >> 4) << 2);
    #pragma unroll
    for (int j = 0; j < 4; j++) {
        int row = rbase + j;
        if (row < N) {
            float di = dinv[row];
            unsigned short* p = ppb + (size_t)row * 64 + c;
            p[0]  = f2bf(acc0[j] * di);
            p[16] = f2bf(acc1[j] * di);
            p[32] = f2bf(acc2[j] * di);
            p[48] = f2bf(acc3[j] * di);
        }
    }
}

// G: wave/node. lane = eg*8 + co; edge-group eg (0..7) handles edges
// j0+8q+eg; lane owns cols [8co, 8co+8) via one uint4 (16B) gather.
// 32 edges/iter, 4 independent gathers in flight. No shuffles in edge loop.
__global__ void k_fused1(const int* __restrict__ offs, const int* __restrict__ csr,
                         const unsigned short* __restrict__ ppb,
                         const float* __restrict__ dinv, const float* __restrict__ b1,
                         const float* __restrict__ W2, float* __restrict__ qp, int N) {
    int t = blockIdx.x * blockDim.x + threadIdx.x;
    int lane = t & 63;
    int eg = lane >> 3;          // edge group 0..7
    int c0 = (lane & 7) << 3;    // col base: 8 cols per lane
    int node = t >> 6;
    int nstride = (gridDim.x * blockDim.x) >> 6;
    float4 wA = *(const float4*)&W2[c0];
    float4 wB = *(const float4*)&W2[c0 + 4];
    float4 bA = *(const float4*)&b1[c0];
    float4 bB = *(const float4*)&b1[c0 + 4];
    for (; node < N; node += nstride) {
        int start = offs[node], end = offs[node + 1];
        float a0 = 0.f, a1 = 0.f, a2 = 0.f, a3 = 0.f;
        float a4 = 0.f, a5 = 0.f, a6 = 0.f, a7 = 0.f;
        if (eg == 0) {   // self-loop term, counted once (group 0 only)
            uint4 v = *(const uint4*)&ppb[(size_t)node * 64 + c0];
            a0 += bf2f((unsigned short)(v.x & 0xffffu));
            a1 += bf2f((unsigned short)(v.x >> 16));
            a2 += bf2f((unsigned short)(v.y & 0xffffu));
            a3 += bf2f((unsigned short)(v.y >> 16));
            a4 += bf2f((unsigned short)(v.z & 0xffffu));
            a5 += bf2f((unsigned short)(v.z >> 16));
            a6 += bf2f((unsigned short)(v.w & 0xffffu));
            a7 += bf2f((unsigned short)(v.w >> 16));
        }
        for (int j0 = start; j0 < end; j0 += 32) {   // 32 edges/iter, 4/group
            bool act[4]; int idx[4];
            #pragma unroll
            for (int q = 0; q < 4; q++) {
                int jj = j0 + 8 * q + eg;
                act[q] = jj < end;
                idx[q] = csr[act[q] ? jj : end - 1];
            }
            uint4 v[4];
            #pragma unroll
            for (int q = 0; q < 4; q++)
                if (act[q]) v[q] = *(const uint4*)&ppb[(size_t)idx[q] * 64 + c0];
            #pragma unroll
            for (int q = 0; q < 4; q++)
                if (act[q]) {
                    a0 += bf2f((unsigned short)(v[q].x & 0xffffu));
                    a1 += bf2f((unsigned short)(v[q].x >> 16));
                    a2 += bf2f((unsigned short)(v[q].y & 0xffffu));
                    a3 += bf2f((unsigned short)(v[q].y >> 16));
                    a4 += bf2f((unsigned short)(v[q].z & 0xffffu));
                    a5 += bf2f((unsigned short)(v[q].z >> 16));
                    a6 += bf2f((unsigned short)(v[q].w & 0xffffu));
                    a7 += bf2f((unsigned short)(v[q].w >> 16));
                }
        }
        // reduce over edge-group bits (8,16,32); full-exec shuffles
        #pragma unroll
        for (int m = 8; m <= 32; m <<= 1) {
            a0 += __shfl_xor(a0, m, 64); a1 += __shfl_xor(a1, m, 64);
            a2 += __shfl_xor(a2, m, 64); a3 += __shfl_xor(a3, m, 64);
            a4 += __shfl_xor(a4, m, 64); a5 += __shfl_xor(a5, m, 64);
            a6 += __shfl_xor(a6, m, 64); a7 += __shfl_xor(a7, m, 64);
        }
        float di = dinv[node];
        float v = fmaxf(di * a0 + bA.x, 0.f) * wA.x
                + fmaxf(di * a1 + bA.y, 0.f) * wA.y
                + fmaxf(di * a2 + bA.z, 0.f) * wA.z
                + fmaxf(di * a3 + bA.w, 0.f) * wA.w
                + fmaxf(di * a4 + bB.x, 0.f) * wB.x
                + fmaxf(di * a5 + bB.y, 0.f) * wB.y
                + fmaxf(di * a6 + bB.z, 0.f) * wB.z
                + fmaxf(di * a7 + bB.w, 0.f) * wB.w;
        // reduce over col bits (1,2,4)
        v += __shfl_xor(v, 1, 64);
        v += __shfl_xor(v, 2, 64);
        v += __shfl_xor(v, 4, 64);
        if (lane == 0) qp[node] = v * di;
    }
}

// H: out = dinv*(qp[self] + sum qp[csr]) + b2; 4 gathers in flight
__global__ void k_fused2(const int* __restrict__ offs, const int* __restrict__ csr,
                         const float* __restrict__ qp, const float* __restrict__ dinv,
                         const float* __restrict__ b2, float* __restrict__ out, int N) {
    int i = blockIdx.x * blockDim.x + threadIdx.x;
    if (i < N) {
        int start = offs[i], end = offs[i + 1];
        float s = qp[i];
        int j = start;
        for (; j + 4 <= end; j += 4) {
            int c0 = csr[j], c1 = csr[j + 1], c2 = csr[j + 2], c3 = csr[j + 3];
            float q0 = qp[c0], q1 = qp[c1], q2 = qp[c2], q3 = qp[c3];
            s += (q0 + q1) + (q2 + q3);
        }
        for (; j < end; j++) s += qp[csr[j]];
        out[i] = dinv[i] * s + b2[0];
    }
}

extern "C" void kernel_launch(void* const* d_in, const int* in_sizes, int n_in,
                              void* d_out, int out_size, void* d_ws, size_t ws_size,
                              hipStream_t stream) {
    const float* x  = (const float*)d_in[0];
    const int*   ei = (const int*)d_in[1];
    const float* W1 = (const float*)d_in[2];
    const float* b1 = (const float*)d_in[3];
    const float* W2 = (const float*)d_in[4];
    const float* b2 = (const float*)d_in[5];
    float* out = (float*)d_out;

    int N = in_sizes[0] / 128;
    int E = in_sizes[1] / 2;
    const int* src = ei;
    const int* dst = ei + E;
    int NB = (N + 255) >> 8;
    int chunk = (E + NBLK - 1) / NBLK;

    size_t Np = ((size_t)N + 255) & ~(size_t)255;
    size_t Ep = ((size_t)E + 255) & ~(size_t)255;
    char* w = (char*)d_ws;
    int* bh      = (int*)w;            w += (size_t)NBLK * 512 * 4;
    int* btot    = (int*)w;            w += 512 * 4;
    int* bbase   = (int*)w;            w += 512 * 4;
    unsigned int* grouped = (unsigned int*)w;  w += Ep * 4;
    int* offs    = (int*)w;            w += (Np + 256) * 4;
    int* csr     = (int*)w;            w += Ep * 4;
    float* dinv  = (float*)w;          w += Np * 4;
    unsigned short* ppb = (unsigned short*)w;  w += Np * 64 * 2;
    float* qp    = (float*)w;          w += Np * 4;
    unsigned short* Bfrag = (unsigned short*)w;  /* 8192 ushorts */

    k_hist<<<NBLK, 256, 0, stream>>>(dst, E, chunk, NB, bh);
    k_bscan<<<NB, 256, 0, stream>>>(bh, NB, btot);
    k_cscan<<<1, 512, 0, stream>>>(btot, NB, E, bbase, offs, N, W1, Bfrag);
    k_dscatter<<<NBLK, 256, 0, stream>>>(src, dst, E, chunk, bh, bbase, NB, grouped);
    k_bfill<<<NB, 256, 0, stream>>>(grouped, bbase, btot, N, offs, csr, dinv);
    k_gemm1m<<<(N + 63) / 64, 256, 0, stream>>>(x, Bfrag, dinv, ppb, N);
    k_fused1<<<2048, 256, 0, stream>>>(offs, csr, ppb, dinv, b1, W2, qp, N);
    k_fused2<<<(N + 255) / 256, 256, 0, stream>>>(offs, csr, qp, dinv, b2, out, N);
}